// Round 1
// baseline (6051.884 us; speedup 1.0000x reference)
//
#include <hip/hip_runtime.h>
#include <stdint.h>

#define T_LEN 2048
#define L     1024
#define KBLK  64            // compute blocks (block KBLK is the gold block)
#define CPB   16            // columns per block = L / KBLK
#define TPB   256
#define EPITCH 520          // (L/2) u32 bf16-pairs per column + 8 pad (breaks bank conflicts)
#define SPIN_MAX (1 << 17)

#define SCOPE_AGENT __HIP_MEMORY_SCOPE_AGENT

__device__ __forceinline__ uint64_t pack_su(int tag, float v) {
    return ((uint64_t)(uint32_t)tag << 32) | (uint64_t)__float_as_uint(v);
}
// fp32 -> bf16 bits, round-to-nearest-even (unbiased; one-sided truncation would bias log(r))
__device__ __forceinline__ uint32_t f2bf(float v) {
    uint32_t x = __float_as_uint(v);
    return (x + 0x7fffu + ((x >> 16) & 1u)) >> 16;
}

__global__ __launch_bounds__(TPB)
void crf_forward(const float* __restrict__ feats,
                 const float* __restrict__ transfer,
                 const int* __restrict__ target,
                 float* __restrict__ out,
                 uint64_t* __restrict__ ws64)
{
    __shared__ uint32_t Epair[CPB * EPITCH];        // ~33 KB: exp(transfer) slice, bf16 pairs, col-major
    __shared__ __align__(16) float q[L];            // 4 KB: exp(prev - s0)
    __shared__ float red[8];

    uint64_t* buf0 = ws64;                          // tagged score buffers (double-buffered)
    uint64_t* buf1 = ws64 + L;
    uint64_t* goldslot = ws64 + 2 * L;

    const int b   = blockIdx.x;
    const int tid = threadIdx.x;

    // ---------------- gold-score block (independent of the chain) ----------------
    if (b == KBLK) {
        float s = 0.f;
        for (int t = tid; t < T_LEN; t += TPB)
            s += feats[t * L + target[t]];
        for (int t = tid; t < T_LEN - 1; t += TPB)
            s += transfer[target[t] * L + target[t + 1]];
        #pragma unroll
        for (int m = 32; m; m >>= 1) s += __shfl_xor(s, m, 64);
        if ((tid & 63) == 0) red[tid >> 6] = s;
        __syncthreads();
        if (tid == 0) {
            float g = red[0] + red[1] + red[2] + red[3];
            __hip_atomic_store(goldslot, pack_su(1, g), __ATOMIC_RELAXED, SCOPE_AGENT);
        }
        return;
    }

    // ---------------- stage E = exp(transfer) slice into LDS as bf16 pairs ----------------
    {
        const int col  = tid & 15;                   // local column 0..15
        const int psub = tid >> 4;                   // pair-subgroup 0..15
        const int gcol = b * CPB + col;
        for (int pp = psub; pp < L / 2; pp += 16) {
            float e0 = __expf(transfer[(2 * pp)     * L + gcol]);
            float e1 = __expf(transfer[(2 * pp + 1) * L + gcol]);
            Epair[col * EPITCH + pp] = (f2bf(e1) << 16) | f2bf(e0);
        }
    }

    // ---------------- init: step-0 scores = feats[0], tag 0 ----------------
    if (tid < CPB) {
        int j = b * CPB + tid;
        __hip_atomic_store(&buf0[j], pack_su(0, feats[j]), __ATOMIC_RELAXED, SCOPE_AGENT);
    }
    __syncthreads();

    const int c  = tid >> 4;                         // column within block 0..15
    const int il = tid & 15;                         // i-group 0..15
    const int jglob = b * CPB + c;

    // ---------------- sequential chain ----------------
    for (int t = 1; t < T_LEN; ++t) {
        uint64_t* rbuf = (t & 1) ? buf0 : buf1;      // holds step t-1
        uint64_t* wbuf = (t & 1) ? buf1 : buf0;      // will hold step t
        const int expect = t - 1;

        // prefetch emission for the writer lane (off critical path)
        float fval = 0.f;
        if (il == 0) fval = feats[t * L + jglob];

        // tag-spin loads: s0 (reference score, column 0) + this thread's 4 columns
        uint64_t u = __hip_atomic_load(&rbuf[0], __ATOMIC_RELAXED, SCOPE_AGENT);
        int n = 0;
        while ((int)(u >> 32) < expect && ++n < SPIN_MAX)
            u = __hip_atomic_load(&rbuf[0], __ATOMIC_RELAXED, SCOPE_AGENT);
        const float s0 = __uint_as_float((uint32_t)u);

        float sv[4];
        #pragma unroll
        for (int k = 0; k < 4; ++k) {
            const int idx = tid + TPB * k;
            uint64_t v = __hip_atomic_load(&rbuf[idx], __ATOMIC_RELAXED, SCOPE_AGENT);
            n = 0;
            while ((int)(v >> 32) < expect && ++n < SPIN_MAX)
                v = __hip_atomic_load(&rbuf[idx], __ATOMIC_RELAXED, SCOPE_AGENT);
            sv[k] = __uint_as_float((uint32_t)v);
        }

        // q[i] = exp(prev[i] - s0)   (s0-shift is stable: label-score spread << 87)
        #pragma unroll
        for (int k = 0; k < 4; ++k)
            q[tid + TPB * k] = __expf(sv[k] - s0);
        __syncthreads();

        // matvec: r[c] = sum_i q[i] * E[i, c]  (16 lanes per column, bf16-pair E)
        float acc0 = 0.f, acc1 = 0.f;
        const float2* q2 = (const float2*)q;
        const uint32_t* Ep = &Epair[c * EPITCH];
        #pragma unroll
        for (int k = 0; k < 32; k += 2) {
            const int p0 = il + 16 * k;
            const uint32_t u0 = Ep[p0];
            const float2 qa = q2[p0];
            acc0 += qa.x * __uint_as_float(u0 << 16);
            acc0 += qa.y * __uint_as_float(u0 & 0xffff0000u);
            const int p1 = il + 16 * (k + 1);
            const uint32_t u1 = Ep[p1];
            const float2 qb = q2[p1];
            acc1 += qb.x * __uint_as_float(u1 << 16);
            acc1 += qb.y * __uint_as_float(u1 & 0xffff0000u);
        }
        float acc = acc0 + acc1;
        #pragma unroll
        for (int m = 8; m; m >>= 1) acc += __shfl_xor(acc, m, 16);

        if (il == 0) {
            const float nv = s0 + __logf(acc) + fval;
            __hip_atomic_store(&wbuf[jglob], pack_su(t, nv), __ATOMIC_RELAXED, SCOPE_AGENT);
        }
        __syncthreads();   // protects q[] before next iteration overwrites it
    }

    // ---------------- epilogue: block 0 computes logZ - gold ----------------
    if (b == 0) {
        float sv[4];
        #pragma unroll
        for (int k = 0; k < 4; ++k) {
            const int idx = tid + TPB * k;
            uint64_t v = __hip_atomic_load(&buf1[idx], __ATOMIC_RELAXED, SCOPE_AGENT);
            int n = 0;
            while ((int)(v >> 32) < T_LEN - 1 && ++n < SPIN_MAX)
                v = __hip_atomic_load(&buf1[idx], __ATOMIC_RELAXED, SCOPE_AGENT);
            sv[k] = __uint_as_float((uint32_t)v);
        }
        float mx = fmaxf(fmaxf(sv[0], sv[1]), fmaxf(sv[2], sv[3]));
        #pragma unroll
        for (int m = 32; m; m >>= 1) mx = fmaxf(mx, __shfl_xor(mx, m, 64));
        if ((tid & 63) == 0) red[tid >> 6] = mx;
        __syncthreads();
        const float M = fmaxf(fmaxf(red[0], red[1]), fmaxf(red[2], red[3]));
        float s = 0.f;
        #pragma unroll
        for (int k = 0; k < 4; ++k) s += __expf(sv[k] - M);
        #pragma unroll
        for (int m = 32; m; m >>= 1) s += __shfl_xor(s, m, 64);
        if ((tid & 63) == 0) red[4 + (tid >> 6)] = s;
        __syncthreads();
        if (tid == 0) {
            const float S = red[4] + red[5] + red[6] + red[7];
            const float lse = M + __logf(S);
            uint64_t g = __hip_atomic_load(goldslot, __ATOMIC_RELAXED, SCOPE_AGENT);
            int n = 0;
            while ((int)(g >> 32) < 1 && ++n < SPIN_MAX)
                g = __hip_atomic_load(goldslot, __ATOMIC_RELAXED, SCOPE_AGENT);
            out[0] = lse - __uint_as_float((uint32_t)g);
        }
    }
}

extern "C" void kernel_launch(void* const* d_in, const int* in_sizes, int n_in,
                              void* d_out, int out_size, void* d_ws, size_t ws_size,
                              hipStream_t stream) {
    const float* feats    = (const float*)d_in[0];
    const float* transfer = (const float*)d_in[1];
    const int*   target   = (const int*)d_in[2];
    float* out = (float*)d_out;
    uint64_t* ws64 = (uint64_t*)d_ws;   // needs (2*L + 1) * 8 = 16392 bytes

    hipLaunchKernelGGL(crf_forward, dim3(KBLK + 1), dim3(TPB), 0, stream,
                       feats, transfer, target, out, ws64);
}

// Round 2
// 5032.327 us; speedup vs baseline: 1.2026x; 1.2026x over previous
//
#include <hip/hip_runtime.h>
#include <stdint.h>

#define T_LEN 2048
#define L     1024
#define KBLK  64            // compute blocks (block KBLK is the gold block)
#define CPB   16            // columns per block = L / KBLK
#define TPB   256
#define EP2   257           // uint2 pitch per column (256 + 1 pad)
#define SPIN_MAX (1 << 17)

#define SCOPE_AGENT __HIP_MEMORY_SCOPE_AGENT

__device__ __forceinline__ uint64_t pack_su(int tag, float v) {
    return ((uint64_t)(uint32_t)tag << 32) | (uint64_t)__float_as_uint(v);
}
// fp32 -> bf16 bits, round-to-nearest-even
__device__ __forceinline__ uint32_t f2bf(float v) {
    uint32_t x = __float_as_uint(v);
    return (x + 0x7fffu + ((x >> 16) & 1u)) >> 16;
}
__device__ __forceinline__ float bflo(uint32_t u) { return __uint_as_float(u << 16); }
__device__ __forceinline__ float bfhi(uint32_t u) { return __uint_as_float(u & 0xffff0000u); }

__global__ __launch_bounds__(TPB)
void crf_forward(const float* __restrict__ feats,
                 const float* __restrict__ transfer,
                 const int* __restrict__ target,
                 float* __restrict__ out,
                 uint64_t* __restrict__ ws64)
{
    __shared__ uint2 Ew[CPB * EP2];                 // ~33 KB: exp(transfer) slice, bf16 pairs
    __shared__ __align__(16) float q[2][L];         // 8 KB: exp(prev - sloc), double-buffered
    __shared__ float red[8];
    __shared__ float slocal;                        // block-uniform exp shift (prev step, col 0)

    uint64_t* buf0 = ws64;                          // tagged score buffers (double-buffered)
    uint64_t* buf1 = ws64 + L;
    uint64_t* goldslot = ws64 + 2 * L;

    const int b   = blockIdx.x;
    const int tid = threadIdx.x;

    // ---------------- gold-score block (independent of the chain) ----------------
    if (b == KBLK) {
        float s = 0.f;
        for (int t = tid; t < T_LEN; t += TPB)
            s += feats[t * L + target[t]];
        for (int t = tid; t < T_LEN - 1; t += TPB)
            s += transfer[target[t] * L + target[t + 1]];
        #pragma unroll
        for (int m = 32; m; m >>= 1) s += __shfl_xor(s, m, 64);
        if ((tid & 63) == 0) red[tid >> 6] = s;
        __syncthreads();
        if (tid == 0) {
            float g = red[0] + red[1] + red[2] + red[3];
            __hip_atomic_store(goldslot, pack_su(1, g), __ATOMIC_RELAXED, SCOPE_AGENT);
        }
        return;
    }

    // ---------------- stage E = exp(transfer) slice into LDS as bf16 pairs ----------------
    {
        const int col  = tid & 15;                   // local column 0..15
        const int sub  = tid >> 4;                   // 0..15
        const int gcol = b * CPB + col;
        for (int m = sub; m < 256; m += 16) {        // m covers labels i = 4m..4m+3
            float e0 = __expf(transfer[(4 * m + 0) * L + gcol]);
            float e1 = __expf(transfer[(4 * m + 1) * L + gcol]);
            float e2 = __expf(transfer[(4 * m + 2) * L + gcol]);
            float e3 = __expf(transfer[(4 * m + 3) * L + gcol]);
            Ew[col * EP2 + m] = make_uint2((f2bf(e1) << 16) | f2bf(e0),
                                           (f2bf(e3) << 16) | f2bf(e2));
        }
    }

    // ---------------- init: step-0 scores = feats[0], tag 0 ----------------
    if (tid < CPB) {
        int j = b * CPB + tid;
        __hip_atomic_store(&buf0[j], pack_su(0, feats[j]), __ATOMIC_RELAXED, SCOPE_AGENT);
    }
    if (tid == 0) slocal = feats[b * CPB];           // true score of column b*16 at t=0
    __syncthreads();

    const int c  = tid >> 4;                         // column within block 0..15
    const int il = tid & 15;                         // i-group 0..15
    const int jglob = b * CPB + c;

    // ---------------- sequential chain ----------------
    for (int t = 1; t < T_LEN; ++t) {
        uint64_t* rbuf = (t & 1) ? buf0 : buf1;      // holds step t-1
        uint64_t* wbuf = (t & 1) ? buf1 : buf0;      // will hold step t
        const int expect = t - 1;

        // prefetch emission for the writer lane (overlaps the poll)
        float fval = 0.f;
        if (il == 0) fval = feats[t * L + jglob];

        // parallel tag-spin: 4 contiguous slots, all loads in flight together
        const uint64_t* rp = rbuf + 4 * tid;
        uint64_t v0, v1, v2, v3;
        int n = 0;
        for (;;) {
            v0 = __hip_atomic_load(rp + 0, __ATOMIC_RELAXED, SCOPE_AGENT);
            v1 = __hip_atomic_load(rp + 1, __ATOMIC_RELAXED, SCOPE_AGENT);
            v2 = __hip_atomic_load(rp + 2, __ATOMIC_RELAXED, SCOPE_AGENT);
            v3 = __hip_atomic_load(rp + 3, __ATOMIC_RELAXED, SCOPE_AGENT);
            bool ready = ((int)(v0 >> 32) >= expect) & ((int)(v1 >> 32) >= expect) &
                         ((int)(v2 >> 32) >= expect) & ((int)(v3 >> 32) >= expect);
            if (ready || ++n >= SPIN_MAX) break;
        }

        __syncthreads();                             // fence: slocal(t-1) safe; q[t&1] free
        const float sloc = slocal;

        float* qb = q[t & 1];
        float4 qv;
        qv.x = __expf(__uint_as_float((uint32_t)v0) - sloc);
        qv.y = __expf(__uint_as_float((uint32_t)v1) - sloc);
        qv.z = __expf(__uint_as_float((uint32_t)v2) - sloc);
        qv.w = __expf(__uint_as_float((uint32_t)v3) - sloc);
        ((float4*)qb)[tid] = qv;
        __syncthreads();

        // matvec: r[c] = sum_i q[i] * E[i, c]  (16 lanes per column, vectorized LDS)
        const float4* q4 = (const float4*)qb;
        const uint2*  Ec = &Ew[c * EP2];
        float acc0 = 0.f, acc1 = 0.f;
        #pragma unroll
        for (int k = 0; k < 16; k += 2) {
            const int m0 = il + 16 * k;
            uint2  e0 = Ec[m0];
            float4 qa = q4[m0];
            acc0 += qa.x * bflo(e0.x) + qa.y * bfhi(e0.x);
            acc0 += qa.z * bflo(e0.y) + qa.w * bfhi(e0.y);
            const int m1 = il + 16 * (k + 1);
            uint2  e1 = Ec[m1];
            float4 qb4 = q4[m1];
            acc1 += qb4.x * bflo(e1.x) + qb4.y * bfhi(e1.x);
            acc1 += qb4.z * bflo(e1.y) + qb4.w * bfhi(e1.y);
        }
        float acc = acc0 + acc1;
        #pragma unroll
        for (int m = 8; m; m >>= 1) acc += __shfl_xor(acc, m, 16);

        if (il == 0) {
            const float nv = sloc + __logf(acc) + fval;
            __hip_atomic_store(&wbuf[jglob], pack_su(t, nv), __ATOMIC_RELAXED, SCOPE_AGENT);
            if (tid == 0) slocal = nv;               // next step's shift (fenced by next barrier)
        }
    }

    // ---------------- epilogue: block 0 computes logZ - gold ----------------
    if (b == 0) {
        const uint64_t* fp = buf1 + 4 * tid;         // t=2047 (odd) wrote buf1
        uint64_t v0, v1, v2, v3;
        int n = 0;
        for (;;) {
            v0 = __hip_atomic_load(fp + 0, __ATOMIC_RELAXED, SCOPE_AGENT);
            v1 = __hip_atomic_load(fp + 1, __ATOMIC_RELAXED, SCOPE_AGENT);
            v2 = __hip_atomic_load(fp + 2, __ATOMIC_RELAXED, SCOPE_AGENT);
            v3 = __hip_atomic_load(fp + 3, __ATOMIC_RELAXED, SCOPE_AGENT);
            bool ready = ((int)(v0 >> 32) >= T_LEN - 1) & ((int)(v1 >> 32) >= T_LEN - 1) &
                         ((int)(v2 >> 32) >= T_LEN - 1) & ((int)(v3 >> 32) >= T_LEN - 1);
            if (ready || ++n >= SPIN_MAX) break;
        }
        float sv[4] = { __uint_as_float((uint32_t)v0), __uint_as_float((uint32_t)v1),
                        __uint_as_float((uint32_t)v2), __uint_as_float((uint32_t)v3) };
        float mx = fmaxf(fmaxf(sv[0], sv[1]), fmaxf(sv[2], sv[3]));
        #pragma unroll
        for (int m = 32; m; m >>= 1) mx = fmaxf(mx, __shfl_xor(mx, m, 64));
        if ((tid & 63) == 0) red[tid >> 6] = mx;
        __syncthreads();
        const float M = fmaxf(fmaxf(red[0], red[1]), fmaxf(red[2], red[3]));
        float s = 0.f;
        #pragma unroll
        for (int k = 0; k < 4; ++k) s += __expf(sv[k] - M);
        #pragma unroll
        for (int m = 32; m; m >>= 1) s += __shfl_xor(s, m, 64);
        if ((tid & 63) == 0) red[4 + (tid >> 6)] = s;
        __syncthreads();
        if (tid == 0) {
            const float S = red[4] + red[5] + red[6] + red[7];
            const float lse = M + __logf(S);
            uint64_t g = __hip_atomic_load(goldslot, __ATOMIC_RELAXED, SCOPE_AGENT);
            int n2 = 0;
            while ((int)(g >> 32) < 1 && ++n2 < SPIN_MAX)
                g = __hip_atomic_load(goldslot, __ATOMIC_RELAXED, SCOPE_AGENT);
            out[0] = lse - __uint_as_float((uint32_t)g);
        }
    }
}

extern "C" void kernel_launch(void* const* d_in, const int* in_sizes, int n_in,
                              void* d_out, int out_size, void* d_ws, size_t ws_size,
                              hipStream_t stream) {
    const float* feats    = (const float*)d_in[0];
    const float* transfer = (const float*)d_in[1];
    const int*   target   = (const int*)d_in[2];
    float* out = (float*)d_out;
    uint64_t* ws64 = (uint64_t*)d_ws;   // needs (2*L + 1) * 8 = 16392 bytes

    hipLaunchKernelGGL(crf_forward, dim3(KBLK + 1), dim3(TPB), 0, stream,
                       feats, transfer, target, out, ws64);
}